// Round 1
// baseline (1319.426 us; speedup 1.0000x reference)
//
#include <hip/hip_runtime.h>

#define HC   128   // H*C
#define FE   16    // edge feature dim
#define NEG  0.2f

static __device__ __forceinline__ size_t szt(int a) { return (size_t)a; }

// ---------------- CSR build ----------------

__global__ void k_count(const int* __restrict__ dst, int* __restrict__ cnt, int E) {
    int e = blockIdx.x * 256 + threadIdx.x;
    if (e < E) atomicAdd(&cnt[dst[e]], 1);
}

// Single-block exclusive scan of (cnt[i]+1); also seeds cursor and the self-loop
// entry eid[row_off[i]] = E+i (self-loop is always FIRST in each node's list).
__global__ __launch_bounds__(1024) void k_scan(const int* __restrict__ cnt,
                                               int* __restrict__ row_off,
                                               int* __restrict__ cursor,
                                               int* __restrict__ eid,
                                               int n, int E) {
    __shared__ int wsum[16];
    __shared__ int carry_s;
    int t = threadIdx.x, lane = t & 63, wv = t >> 6;
    if (t == 0) carry_s = 0;
    __syncthreads();
    for (int base = 0; base < n; base += 1024) {
        int i = base + t;
        int v = (i < n) ? cnt[i] + 1 : 0;
        int s = v;
        #pragma unroll
        for (int d = 1; d < 64; d <<= 1) { int u = __shfl_up(s, d); if (lane >= d) s += u; }
        if (lane == 63) wsum[wv] = s;
        __syncthreads();
        if (t < 16) {
            int ws = wsum[t];
            #pragma unroll
            for (int d = 1; d < 16; d <<= 1) { int u = __shfl_up(ws, d); if (t >= d) ws += u; }
            wsum[t] = ws;
        }
        __syncthreads();
        int excl = carry_s + (wv ? wsum[wv - 1] : 0) + (s - v);
        if (i < n) { row_off[i] = excl; cursor[i] = excl + 1; eid[excl] = E + i; }
        __syncthreads();
        if (t == 0) carry_s += wsum[15];
        __syncthreads();
    }
    if (t == 0) row_off[n] = carry_s;
}

__global__ void k_fill(const int* __restrict__ dst, int* __restrict__ cursor,
                       int* __restrict__ eid, int E) {
    int e = blockIdx.x * 256 + threadIdx.x;
    if (e < E) { int pos = atomicAdd(&cursor[dst[e]], 1); eid[pos] = e; }
}

// ---------------- self-loop edge attr: mean of incoming edge_attr ----------------

__global__ void k_loopattr(const float* __restrict__ edge_attr, const int* __restrict__ eid,
                           const int* __restrict__ row_off, float* __restrict__ loop_attr,
                           int n) {
    int t = threadIdx.x;
    int node = blockIdx.x * 16 + (t >> 4);
    if (node >= n) return;
    int comp = t & 15;
    int beg = row_off[node] + 1;   // skip self-loop (always first)
    int end = row_off[node + 1];
    float sum = 0.f;
    for (int p = beg; p < end; ++p) {
        int e = eid[p];            // guaranteed real edge (< E)
        sum += edge_attr[szt(e) * FE + comp];
    }
    int c = end - beg;
    loop_attr[szt(node) * FE + comp] = sum / (float)(c > 0 ? c : 1);
}

// ---------------- fused projection GEMM: xl = x@Wl, xr = x@Wr ----------------
// block = 256 threads: threads 0..127 -> Wl column c, 128..255 -> Wr column c.
// 32 rows of x staged in LDS; LDS reads are wave-uniform broadcasts.

__global__ __launch_bounds__(256) void k_gemm(const float* __restrict__ x,
                                              const float* __restrict__ Wl,
                                              const float* __restrict__ Wr,
                                              float* __restrict__ xl,
                                              float* __restrict__ xr, int n) {
    __shared__ float xs[32][HC];
    int t = threadIdx.x;
    int base = blockIdx.x * 32;
    int rmax = n - base; if (rmax > 32) rmax = 32;
    for (int idx = t; idx < 32 * HC; idx += 256) {
        int r = idx >> 7, k = idx & 127;
        xs[r][k] = (r < rmax) ? x[szt(base + r) * HC + k] : 0.f;
    }
    __syncthreads();
    const float* W = (t & 128) ? Wr : Wl;
    float*       O = (t & 128) ? xr : xl;
    int c = t & 127;
    float acc[32];
    #pragma unroll
    for (int r = 0; r < 32; ++r) acc[r] = 0.f;
    for (int k = 0; k < HC; k += 4) {
        float w0 = W[(k + 0) * HC + c];
        float w1 = W[(k + 1) * HC + c];
        float w2 = W[(k + 2) * HC + c];
        float w3 = W[(k + 3) * HC + c];
        #pragma unroll
        for (int r = 0; r < 32; ++r) {
            float4 xv = *reinterpret_cast<const float4*>(&xs[r][k]);
            acc[r] += xv.x * w0 + xv.y * w1 + xv.z * w2 + xv.w * w3;
        }
    }
    #pragma unroll
    for (int r = 0; r < 32; ++r)
        if (r < rmax) O[szt(base + r) * HC + c] = acc[r];
}

// ---------------- fused per-node attention + aggregation ----------------
// 1 wave per node; lane owns channels (2*lane, 2*lane+1); head = lane/16.
// Writes unnormalized exp(logit) into alpha, denom per (node,head), and the
// final relu(out) (division by denom folded into the epilogue).

__global__ __launch_bounds__(256) void k_fused(
    const float* __restrict__ xl, const float* __restrict__ xr,
    const float* __restrict__ edge_attr, const float* __restrict__ loop_attr,
    const int* __restrict__ src, const int* __restrict__ eid,
    const int* __restrict__ row_off, const float* __restrict__ We,
    const float* __restrict__ att, const float* __restrict__ bias,
    float* __restrict__ out, float* __restrict__ alpha,
    float* __restrict__ denom_out, int n, int E)
{
    __shared__ float sWe[FE * HC];
    __shared__ float sAtt[HC];
    __shared__ float sBias[HC];
    for (int i = threadIdx.x; i < FE * HC; i += 256) sWe[i] = We[i];
    if (threadIdx.x < HC) { sAtt[threadIdx.x] = att[threadIdx.x]; sBias[threadIdx.x] = bias[threadIdx.x]; }
    __syncthreads();

    int lane = threadIdx.x & 63, wv = threadIdx.x >> 6;
    int node = blockIdx.x * 4 + wv;
    if (node >= n) return;
    int c0 = lane * 2, c1 = c0 + 1;
    float a0 = sAtt[c0], a1 = sAtt[c1];
    float xr0 = xr[szt(node) * HC + c0], xr1 = xr[szt(node) * HC + c1];
    int beg = row_off[node], end = row_off[node + 1];
    float acc0 = 0.f, acc1 = 0.f, den = 0.f;

    // 1-deep software pipeline on the xl gather
    int e_c; const float* ea_c; float v0_c, v1_c;
    {
        int e = eid[beg]; int s;
        if (e < E) { s = src[e];  ea_c = edge_attr + szt(e) * FE; }
        else       { s = e - E;   ea_c = loop_attr + szt(s) * FE; }
        e_c = e;
        v0_c = xl[szt(s) * HC + c0]; v1_c = xl[szt(s) * HC + c1];
    }
    for (int p = beg; p < end; ++p) {
        int e_n = 0; const float* ea_n = ea_c; float v0_n = 0.f, v1_n = 0.f;
        if (p + 1 < end) {
            int e = eid[p + 1]; int s;
            if (e < E) { s = src[e];  ea_n = edge_attr + szt(e) * FE; }
            else       { s = e - E;   ea_n = loop_attr + szt(s) * FE; }
            e_n = e;
            v0_n = xl[szt(s) * HC + c0]; v1_n = xl[szt(s) * HC + c1];
        }
        float ee0 = 0.f, ee1 = 0.f;
        #pragma unroll
        for (int k = 0; k < FE; ++k) {
            float ev = ea_c[k];
            ee0 += ev * sWe[k * HC + c0];
            ee1 += ev * sWe[k * HC + c1];
        }
        float t0 = v0_c + xr0 + ee0, t1 = v1_c + xr1 + ee1;
        t0 = t0 > 0.f ? t0 : NEG * t0;
        t1 = t1 > 0.f ? t1 : NEG * t1;
        float part = a0 * t0 + a1 * t1;
        part += __shfl_xor(part, 1);
        part += __shfl_xor(part, 2);
        part += __shfl_xor(part, 4);
        part += __shfl_xor(part, 8);
        float expl = __expf(part);   // logits are small: no max-subtraction needed
        den += expl;
        acc0 += expl * v0_c;
        acc1 += expl * v1_c;
        if ((lane & 15) == 0) alpha[szt(e_c) * 4 + (lane >> 4)] = expl;
        e_c = e_n; ea_c = ea_n; v0_c = v0_n; v1_c = v1_n;
    }
    float inv = 1.f / den;
    if ((lane & 15) == 0) denom_out[szt(node) * 4 + (lane >> 4)] = den;
    float o0 = acc0 * inv + sBias[c0];
    float o1 = acc1 * inv + sBias[c1];
    out[szt(node) * HC + c0] = o0 > 0.f ? o0 : 0.f;
    out[szt(node) * HC + c1] = o1 > 0.f ? o1 : 0.f;
}

// ---------------- alpha normalization (separate kernel => no fence games) ----------------

__global__ void k_norm(const int* __restrict__ dst, const float* __restrict__ denom,
                       float* __restrict__ alpha, int n, int E) {
    int e = blockIdx.x * 256 + threadIdx.x;
    int tot = E + n;
    if (e >= tot) return;
    int d = (e < E) ? dst[e] : (e - E);
    float4 a  = *reinterpret_cast<const float4*>(&alpha[szt(e) * 4]);
    float4 dn = *reinterpret_cast<const float4*>(&denom[szt(d) * 4]);
    a.x /= dn.x; a.y /= dn.y; a.z /= dn.z; a.w /= dn.w;
    *reinterpret_cast<float4*>(&alpha[szt(e) * 4]) = a;
}

// ---------------- launch ----------------

extern "C" void kernel_launch(void* const* d_in, const int* in_sizes, int n_in,
                              void* d_out, int out_size, void* d_ws, size_t ws_size,
                              hipStream_t stream) {
    const float* x    = (const float*)d_in[0];
    const int*   ei   = (const int*)d_in[1];
    const float* ea   = (const float*)d_in[2];
    const float* Wl   = (const float*)d_in[3];
    const float* Wr   = (const float*)d_in[4];
    const float* We   = (const float*)d_in[5];
    const float* att  = (const float*)d_in[6];
    const float* bias = (const float*)d_in[7];

    const int n = in_sizes[0] / HC;   // F_IN == 128
    const int E = in_sizes[1] / 2;
    const int* src = ei;
    const int* dst = ei + E;

    char* w = (char*)d_ws;
    size_t off = 0;
    auto alloc = [&](size_t bytes) -> char* {
        char* p = w + off;
        off += (bytes + 255) & ~(size_t)255;
        return p;
    };
    float* xl        = (float*)alloc((size_t)n * HC * 4);
    float* xr        = (float*)alloc((size_t)n * HC * 4);
    float* loop_attr = (float*)alloc((size_t)n * FE * 4);
    float* denom     = (float*)alloc((size_t)n * 4 * 4);
    int*   cnt       = (int*)  alloc((size_t)n * 4);
    int*   row_off   = (int*)  alloc((size_t)(n + 1) * 4);
    int*   cursor    = (int*)  alloc((size_t)n * 4);
    int*   eid       = (int*)  alloc((size_t)(E + n) * 4);
    (void)ws_size;

    float* out_p   = (float*)d_out;
    float* alpha_p = (float*)d_out + (size_t)n * HC;

    hipMemsetAsync(cnt, 0, (size_t)n * 4, stream);
    k_count   <<<(E + 255) / 256, 256, 0, stream>>>(dst, cnt, E);
    k_scan    <<<1, 1024, 0, stream>>>(cnt, row_off, cursor, eid, n, E);
    k_fill    <<<(E + 255) / 256, 256, 0, stream>>>(dst, cursor, eid, E);
    k_loopattr<<<(n + 15) / 16, 256, 0, stream>>>(ea, eid, row_off, loop_attr, n);
    k_gemm    <<<(n + 31) / 32, 256, 0, stream>>>(x, Wl, Wr, xl, xr, n);
    k_fused   <<<(n + 3) / 4, 256, 0, stream>>>(xl, xr, ea, loop_attr, src, eid, row_off,
                                                We, att, bias, out_p, alpha_p, denom, n, E);
    k_norm    <<<(E + n + 255) / 256, 256, 0, stream>>>(dst, denom, alpha_p, n, E);
}

// Round 2
// 865.726 us; speedup vs baseline: 1.5241x; 1.5241x over previous
//
#include <hip/hip_runtime.h>

#define HC   128   // H*C
#define FE   16    // edge feature dim
#define NEG  0.2f

static __device__ __forceinline__ size_t szt(int a) { return (size_t)a; }

// ---------------- CSR build (real edges only; self-loops handled in epilogue) ----------------

__global__ void k_count(const int* __restrict__ dst, int* __restrict__ cnt, int E) {
    int e = blockIdx.x * 256 + threadIdx.x;
    if (e < E) atomicAdd(&cnt[dst[e]], 1);
}

// Single-block exclusive scan of cnt[i]; seeds cursor.
__global__ __launch_bounds__(1024) void k_scan(const int* __restrict__ cnt,
                                               int* __restrict__ row_off,
                                               int* __restrict__ cursor,
                                               int n) {
    __shared__ int wsum[16];
    __shared__ int carry_s;
    int t = threadIdx.x, lane = t & 63, wv = t >> 6;
    if (t == 0) carry_s = 0;
    __syncthreads();
    for (int base = 0; base < n; base += 1024) {
        int i = base + t;
        int v = (i < n) ? cnt[i] : 0;
        int s = v;
        #pragma unroll
        for (int d = 1; d < 64; d <<= 1) { int u = __shfl_up(s, d); if (lane >= d) s += u; }
        if (lane == 63) wsum[wv] = s;
        __syncthreads();
        if (t < 16) {
            int ws = wsum[t];
            #pragma unroll
            for (int d = 1; d < 16; d <<= 1) { int u = __shfl_up(ws, d); if (t >= d) ws += u; }
            wsum[t] = ws;
        }
        __syncthreads();
        int excl = carry_s + (wv ? wsum[wv - 1] : 0) + (s - v);
        if (i < n) { row_off[i] = excl; cursor[i] = excl; }
        __syncthreads();
        if (t == 0) carry_s += wsum[15];
        __syncthreads();
    }
    if (t == 0) row_off[n] = carry_s;
}

__global__ void k_fill(const int* __restrict__ dst, int* __restrict__ cursor,
                       int* __restrict__ eid, int E) {
    int e = blockIdx.x * 256 + threadIdx.x;
    if (e < E) { int pos = atomicAdd(&cursor[dst[e]], 1); eid[pos] = e; }
}

// ---------------- fused projection GEMM: xl = x@Wl, xr = x@Wr ----------------

__global__ __launch_bounds__(256) void k_gemm(const float* __restrict__ x,
                                              const float* __restrict__ Wl,
                                              const float* __restrict__ Wr,
                                              float* __restrict__ xl,
                                              float* __restrict__ xr, int n) {
    __shared__ float xs[32][HC];
    int t = threadIdx.x;
    int base = blockIdx.x * 32;
    int rmax = n - base; if (rmax > 32) rmax = 32;
    for (int idx = t; idx < 32 * HC; idx += 256) {
        int r = idx >> 7, k = idx & 127;
        xs[r][k] = (r < rmax) ? x[szt(base + r) * HC + k] : 0.f;
    }
    __syncthreads();
    const float* W = (t & 128) ? Wr : Wl;
    float*       O = (t & 128) ? xr : xl;
    int c = t & 127;
    float acc[32];
    #pragma unroll
    for (int r = 0; r < 32; ++r) acc[r] = 0.f;
    for (int k = 0; k < HC; k += 4) {
        float w0 = W[(k + 0) * HC + c];
        float w1 = W[(k + 1) * HC + c];
        float w2 = W[(k + 2) * HC + c];
        float w3 = W[(k + 3) * HC + c];
        #pragma unroll
        for (int r = 0; r < 32; ++r) {
            float4 xv = *reinterpret_cast<const float4*>(&xs[r][k]);
            acc[r] += xv.x * w0 + xv.y * w1 + xv.z * w2 + xv.w * w3;
        }
    }
    #pragma unroll
    for (int r = 0; r < 32; ++r)
        if (r < rmax) O[szt(base + r) * HC + c] = acc[r];
}

// ---------------- fused per-node attention + aggregation ----------------
// 1 wave per node; lane owns channels (2*lane, 2*lane+1); head = lane/16.
// 4-wide batched gather pipeline; edge indices/attrs via wave-uniform scalar loads.
// Self-loop handled in the epilogue: ee_self = mean(ee) over incoming edges
// (linearity of ea@We), so no loop_attr buffer/kernel is needed.

__global__ __launch_bounds__(256) void k_fused(
    const float* __restrict__ xl, const float* __restrict__ xr,
    const float* __restrict__ edge_attr,
    const int* __restrict__ src, const int* __restrict__ eid,
    const int* __restrict__ row_off, const float* __restrict__ We,
    const float* __restrict__ att, const float* __restrict__ bias,
    float* __restrict__ out, float* __restrict__ alpha,
    float* __restrict__ denom_out, int n, int E)
{
    __shared__ float sWe[FE * HC];
    __shared__ float sAtt[HC];
    __shared__ float sBias[HC];
    for (int i = threadIdx.x; i < FE * HC; i += 256) sWe[i] = We[i];
    if (threadIdx.x < HC) { sAtt[threadIdx.x] = att[threadIdx.x]; sBias[threadIdx.x] = bias[threadIdx.x]; }
    __syncthreads();

    int lane = threadIdx.x & 63, wv = threadIdx.x >> 6;
    int node = blockIdx.x * 4 + wv;
    if (node >= n) return;
    int c0 = lane * 2;
    int h  = lane >> 4;
    float a0 = sAtt[c0], a1 = sAtt[c0 + 1];
    float2 xrv = *reinterpret_cast<const float2*>(&xr[szt(node) * HC + c0]);
    int beg = row_off[node], end = row_off[node + 1];
    float acc0 = 0.f, acc1 = 0.f, den = 0.f, es0 = 0.f, es1 = 0.f;

    for (int p = beg; p < end; p += 4) {
        int m = end - p; if (m > 4) m = 4;
        int e[4], s[4];
        float2 v[4];
        #pragma unroll
        for (int j = 0; j < 4; ++j) {
            int ej = eid[p + ((j < m) ? j : 0)];
            e[j] = __builtin_amdgcn_readfirstlane(ej);
        }
        #pragma unroll
        for (int j = 0; j < 4; ++j) {
            int sj = src[e[j]];
            s[j] = __builtin_amdgcn_readfirstlane(sj);
        }
        #pragma unroll
        for (int j = 0; j < 4; ++j)
            v[j] = *reinterpret_cast<const float2*>(&xl[szt(s[j]) * HC + c0]);
        #pragma unroll
        for (int j = 0; j < 4; ++j) {
            if (j < m) {
                const float4* eap = reinterpret_cast<const float4*>(edge_attr + szt(e[j]) * FE);
                float4 qa = eap[0], qb = eap[1], qc = eap[2], qd = eap[3];
                const float ev[16] = {qa.x, qa.y, qa.z, qa.w, qb.x, qb.y, qb.z, qb.w,
                                      qc.x, qc.y, qc.z, qc.w, qd.x, qd.y, qd.z, qd.w};
                float ee0 = 0.f, ee1 = 0.f;
                #pragma unroll
                for (int k = 0; k < FE; ++k) {
                    float2 w = *reinterpret_cast<const float2*>(&sWe[k * HC + c0]);
                    ee0 += ev[k] * w.x;
                    ee1 += ev[k] * w.y;
                }
                es0 += ee0; es1 += ee1;
                float t0 = v[j].x + xrv.x + ee0;
                float t1 = v[j].y + xrv.y + ee1;
                t0 = t0 > 0.f ? t0 : NEG * t0;
                t1 = t1 > 0.f ? t1 : NEG * t1;
                float part = a0 * t0 + a1 * t1;
                part += __shfl_xor(part, 1);
                part += __shfl_xor(part, 2);
                part += __shfl_xor(part, 4);
                part += __shfl_xor(part, 8);
                float ex = __expf(part);   // logits are small: no max-subtraction needed
                den  += ex;
                acc0 += ex * v[j].x;
                acc1 += ex * v[j].y;
                if ((lane & 15) == 0) alpha[szt(e[j]) * 4 + h] = ex;
            }
        }
    }

    // self-loop: ee_self = mean over incoming edges of ee (0 if none)
    int deg = end - beg;
    float invd = (deg > 0) ? 1.f / (float)deg : 0.f;
    float ee0 = es0 * invd, ee1 = es1 * invd;
    float2 vs = *reinterpret_cast<const float2*>(&xl[szt(node) * HC + c0]);
    float t0 = vs.x + xrv.x + ee0;
    float t1 = vs.y + xrv.y + ee1;
    t0 = t0 > 0.f ? t0 : NEG * t0;
    t1 = t1 > 0.f ? t1 : NEG * t1;
    float part = a0 * t0 + a1 * t1;
    part += __shfl_xor(part, 1);
    part += __shfl_xor(part, 2);
    part += __shfl_xor(part, 4);
    part += __shfl_xor(part, 8);
    float ex = __expf(part);
    den  += ex;
    acc0 += ex * vs.x;
    acc1 += ex * vs.y;
    if ((lane & 15) == 0) {
        alpha[szt(E + node) * 4 + h] = ex;
        denom_out[szt(node) * 4 + h] = den;
    }
    float inv = 1.f / den;
    float o0 = acc0 * inv + sBias[c0];
    float o1 = acc1 * inv + sBias[c0 + 1];
    float2 ov = make_float2(o0 > 0.f ? o0 : 0.f, o1 > 0.f ? o1 : 0.f);
    *reinterpret_cast<float2*>(&out[szt(node) * HC + c0]) = ov;
}

// ---------------- alpha normalization ----------------

__global__ void k_norm(const int* __restrict__ dst, const float* __restrict__ denom,
                       float* __restrict__ alpha, int n, int E) {
    int e = blockIdx.x * 256 + threadIdx.x;
    int tot = E + n;
    if (e >= tot) return;
    int d = (e < E) ? dst[e] : (e - E);
    float4 a  = *reinterpret_cast<const float4*>(&alpha[szt(e) * 4]);
    float4 dn = *reinterpret_cast<const float4*>(&denom[szt(d) * 4]);
    a.x /= dn.x; a.y /= dn.y; a.z /= dn.z; a.w /= dn.w;
    *reinterpret_cast<float4*>(&alpha[szt(e) * 4]) = a;
}

// ---------------- launch ----------------

extern "C" void kernel_launch(void* const* d_in, const int* in_sizes, int n_in,
                              void* d_out, int out_size, void* d_ws, size_t ws_size,
                              hipStream_t stream) {
    const float* x    = (const float*)d_in[0];
    const int*   ei   = (const int*)d_in[1];
    const float* ea   = (const float*)d_in[2];
    const float* Wl   = (const float*)d_in[3];
    const float* Wr   = (const float*)d_in[4];
    const float* We   = (const float*)d_in[5];
    const float* att  = (const float*)d_in[6];
    const float* bias = (const float*)d_in[7];

    const int n = in_sizes[0] / HC;   // F_IN == 128
    const int E = in_sizes[1] / 2;
    const int* src = ei;
    const int* dst = ei + E;

    char* w = (char*)d_ws;
    size_t off = 0;
    auto alloc = [&](size_t bytes) -> char* {
        char* p = w + off;
        off += (bytes + 255) & ~(size_t)255;
        return p;
    };
    float* xl      = (float*)alloc((size_t)n * HC * 4);
    float* xr      = (float*)alloc((size_t)n * HC * 4);
    float* denom   = (float*)alloc((size_t)n * 4 * 4);
    int*   cnt     = (int*)  alloc((size_t)n * 4);
    int*   row_off = (int*)  alloc((size_t)(n + 1) * 4);
    int*   cursor  = (int*)  alloc((size_t)n * 4);
    int*   eid     = (int*)  alloc((size_t)E * 4);
    (void)ws_size;

    float* out_p   = (float*)d_out;
    float* alpha_p = (float*)d_out + (size_t)n * HC;

    hipMemsetAsync(cnt, 0, (size_t)n * 4, stream);
    k_count<<<(E + 255) / 256, 256, 0, stream>>>(dst, cnt, E);
    k_scan <<<1, 1024, 0, stream>>>(cnt, row_off, cursor, n);
    k_fill <<<(E + 255) / 256, 256, 0, stream>>>(dst, cursor, eid, E);
    k_gemm <<<(n + 31) / 32, 256, 0, stream>>>(x, Wl, Wr, xl, xr, n);
    k_fused<<<(n + 3) / 4, 256, 0, stream>>>(xl, xr, ea, src, eid, row_off,
                                             We, att, bias, out_p, alpha_p, denom, n, E);
    k_norm <<<(E + n + 255) / 256, 256, 0, stream>>>(dst, denom, alpha_p, n, E);
}